// Round 16
// baseline (216.061 us; speedup 1.0000x reference)
//
#include <hip/hip_runtime.h>
#include <hip/hip_bf16.h>
#include <stdint.h>

#define M_DIM 8192
#define N_DIM 4096
#define K_DIM 4096

typedef __attribute__((ext_vector_type(4))) int   int4v;
typedef __attribute__((ext_vector_type(4))) float floatx4;

// ---------------- pre-pass 1: per-row quantize x f32 -> i8, scale = rowmax/127 -------
__global__ __launch_bounds__(256) void quant_x_kernel(const float* __restrict__ x,
                                                      signed char* __restrict__ xq,
                                                      float* __restrict__ xs) {
    const int row = blockIdx.x;
    const int tid = threadIdx.x;
    const int wave = tid >> 6, lane = tid & 63;
    const float4* xr = (const float4*)(x + (size_t)row * K_DIM);

    float4 v[4];
    float m = 0.f;
    #pragma unroll
    for (int j = 0; j < 4; ++j) {
        v[j] = xr[j * 256 + tid];
        m = fmaxf(m, fmaxf(fmaxf(fabsf(v[j].x), fabsf(v[j].y)),
                           fmaxf(fabsf(v[j].z), fabsf(v[j].w))));
    }
    #pragma unroll
    for (int off = 32; off >= 1; off >>= 1) m = fmaxf(m, __shfl_down(m, off));
    __shared__ float wm_s[4];
    if (lane == 0) wm_s[wave] = m;
    __syncthreads();
    const float M = fmaxf(fmaxf(wm_s[0], wm_s[1]), fmaxf(wm_s[2], wm_s[3]));
    const float inv = M > 0.f ? 127.f / M : 0.f;
    if (tid == 0) xs[row] = M > 0.f ? M / 127.f : 0.f;

    char4* xo = (char4*)(xq + (size_t)row * K_DIM);
    #pragma unroll
    for (int j = 0; j < 4; ++j) {
        char4 q;
        q.x = (signed char)__float2int_rn(v[j].x * inv);
        q.y = (signed char)__float2int_rn(v[j].y * inv);
        q.z = (signed char)__float2int_rn(v[j].z * inv);
        q.w = (signed char)__float2int_rn(v[j].w * inv);
        xo[j * 256 + tid] = q;
    }
}

// ------- pre-pass 2: w f32 [K][N] -> sign(w) i8 transposed [N][K] (LDS transpose) ----
__global__ __launch_bounds__(256) void cvt_w_kernel(const float* __restrict__ w,
                                                    signed char* __restrict__ wT) {
    __shared__ signed char tile[64][68];   // pad breaks pow2 column-read stride
    const int t  = threadIdx.x;
    const int k0 = blockIdx.y * 64;
    const int n0 = blockIdx.x * 64;
    #pragma unroll
    for (int p = 0; p < 4; ++p) {
        int kk = p * 16 + (t >> 4);
        int nn = (t & 15) * 4;
        float4 v = *reinterpret_cast<const float4*>(&w[(size_t)(k0 + kk) * N_DIM + n0 + nn]);
        tile[kk][nn + 0] = v.x > 0.f ? 1 : (v.x < 0.f ? -1 : 0);
        tile[kk][nn + 1] = v.y > 0.f ? 1 : (v.y < 0.f ? -1 : 0);
        tile[kk][nn + 2] = v.z > 0.f ? 1 : (v.z < 0.f ? -1 : 0);
        tile[kk][nn + 3] = v.w > 0.f ? 1 : (v.w < 0.f ? -1 : 0);
    }
    __syncthreads();
    const int r = t >> 2;          // local n row
    const int c = (t & 3) * 16;    // local k byte
    int4v o;
    signed char* op = (signed char*)&o;
    #pragma unroll
    for (int j = 0; j < 16; ++j) op[j] = tile[c + j][r];
    *reinterpret_cast<int4v*>(&wT[(size_t)(n0 + r) * K_DIM + k0 + c]) = o;
}

// =====================================================================================
// 256x256 i8 GEMM, FRAGMENT-LEVEL SOFTWARE PIPELINE (read one tile ahead):
//   C = relu( xs[row] * (Xq * signW^T) + bias )
// 8 waves (2M x 4N), 128x64 per wave (best reads/MFMA = 0.375). 4 LDS slots/operand,
// GLD-staged THREE tiles ahead. Fragments double-buffered in registers (static names):
// during tile t the wave issues reads(t+1), then runs MFMA(t) on fragments read during
// t-1 -- the MFMA cluster has ZERO lgkm dependence, so the LDS pipe services reads(t+1)
// fully under MFMA(t) execution (in-wave read/compute overlap, no TLP needed).
// LDS: As[4][2][128*64] + Bs[4][2][128*64] = 128 KiB. Swizzle f(row)=((row>>1)&3)<<4.
// Per tile t: stage (t+3)%4 (4 GLD) ; reads(t+1) slot (t+1)%4 (12 ds_read) ;
//             MFMA(t) x32 (no waits) ; vmcnt(4) ; barrier.
// Ledger (mod 4): reads(t+1) writer staged t-2, retired by end-(t-1) vmcnt(4)
// [outstanding there = (t+1) issued t-2 + (t+2) issued t-1 = 8 -> retires (t+1)].
// Stage slot (t+3)%4 == (t-1)%4: readers were reads(t-1) in tile t-2, lgkm-consumed
// before MFMA(t-1) in tile t-1 < end-(t-1) barrier < this stage. vmcnt(4) at tile end
// retires (t+2) (issued t-1, a full tile ago: never a latency stall).
// Prologue: stage t0,t1,t2 (12 GLD); vmcnt(4) retires t0,t1; reads(0); barrier.
// Registers: 128 acc + 96 frags + misc ~ 239 <= 256 @ launch_bounds(512,2).
// =====================================================================================
#define BM 256
#define BN 256
#define BK 64
#define NT (K_DIM / BK)

#define GLD(gsrc, ldst) __builtin_amdgcn_global_load_lds( \
    (const __attribute__((address_space(1))) unsigned int*)(gsrc), \
    (__attribute__((address_space(3))) unsigned int*)(ldst), 16, 0, 0)

__global__ __launch_bounds__(512, 2) void gemm_i8_kernel(
    const signed char* __restrict__ A,   // [M][K] i8 (quantized x)
    const signed char* __restrict__ BT,  // [N][K] i8 = sign(w)^T
    const float* __restrict__ xsc,       // [M] row scales
    const float* __restrict__ bias,
    float* __restrict__ C)               // [M][N] f32
{
    __shared__ signed char As[4][2][128 * 64];   // 64 KiB
    __shared__ signed char Bs[4][2][128 * 64];   // 64 KiB

    const int tid  = threadIdx.x;
    const int wave = tid >> 6;
    const int lane = tid & 63;
    const int wm   = wave >> 2;        // 0..1 : wave M-half
    const int wn   = wave & 3;         // 0..3 : wave N-slot
    const int bh   = wn >> 1;          // B LDS half this wave reads
    const int brow0 = (wn & 1) * 64;   // row base inside that half

    // XCD-bijective swizzle (nwg = 512, divisible by 8)
    const int bid  = blockIdx.x;
    const int sbid = (bid & 7) * 64 + (bid >> 3);
    const int tn   = sbid & 15;
    const int tm   = sbid >> 4;
    const int bm   = tm * BM;
    const int bn   = tn * BN;

    // staging (write side of swizzle): dest linear o = tid*16; row = tid>>2;
    // source col = ((tid&3) ^ ((tid>>3)&3)) * 16
    const int srow = tid >> 2;
    const int scol = ((tid & 3) ^ ((tid >> 3) & 3)) * 16;

    // fragment read offsets (read side of swizzle)
    const int laneRow = (lane & 15) * 64;
    const int colX = ((lane >> 4) * 16) ^ (((lane >> 1) & 3) << 4);

    int4v acc[8][4] = {};

#define STAGE_HALF(G, R0, KOFS, LDST) do { \
    GLD((G) + (size_t)((R0) + srow) * K_DIM + (KOFS) + scol, (LDST) + wave * 1024); \
  } while (0)

#define STAGE_TILE(SLOT, KOFS) do { \
    STAGE_HALF(A,  bm,       (KOFS), As[SLOT][0]); \
    STAGE_HALF(A,  bm + 128, (KOFS), As[SLOT][1]); \
    STAGE_HALF(BT, bn,       (KOFS), Bs[SLOT][0]); \
    STAGE_HALF(BT, bn + 128, (KOFS), Bs[SLOT][1]); \
  } while (0)

#define READ_FRAGS(SLOT, FA, FA2, FB) do { \
    const char* Ar = (const char*)As[SLOT][wm]; \
    const char* Br = (const char*)Bs[SLOT][bh]; \
    FA[0]  = *(const int4v*)(Ar + (0*16)*64 + laneRow + colX); \
    FB[0]  = *(const int4v*)(Br + (brow0 +  0)*64 + laneRow + colX); \
    FB[1]  = *(const int4v*)(Br + (brow0 + 16)*64 + laneRow + colX); \
    FB[2]  = *(const int4v*)(Br + (brow0 + 32)*64 + laneRow + colX); \
    FB[3]  = *(const int4v*)(Br + (brow0 + 48)*64 + laneRow + colX); \
    FA[1]  = *(const int4v*)(Ar + (1*16)*64 + laneRow + colX); \
    FA[2]  = *(const int4v*)(Ar + (2*16)*64 + laneRow + colX); \
    FA[3]  = *(const int4v*)(Ar + (3*16)*64 + laneRow + colX); \
    FA2[0] = *(const int4v*)(Ar + ((64 + 0*16))*64 + laneRow + colX); \
    FA2[1] = *(const int4v*)(Ar + ((64 + 1*16))*64 + laneRow + colX); \
    FA2[2] = *(const int4v*)(Ar + ((64 + 2*16))*64 + laneRow + colX); \
    FA2[3] = *(const int4v*)(Ar + ((64 + 3*16))*64 + laneRow + colX); \
  } while (0)

#define MFMA_TILE(FA, FA2, FB) do { \
    __builtin_amdgcn_s_setprio(1); \
    _Pragma("unroll") \
    for (int mf = 0; mf < 4; ++mf) \
        _Pragma("unroll") \
        for (int nf = 0; nf < 4; ++nf) \
            acc[mf][nf] = __builtin_amdgcn_mfma_i32_16x16x64_i8( \
                FA[mf], FB[nf], acc[mf][nf], 0, 0, 0); \
    _Pragma("unroll") \
    for (int mf = 0; mf < 4; ++mf) \
        _Pragma("unroll") \
        for (int nf = 0; nf < 4; ++nf) \
            acc[4 + mf][nf] = __builtin_amdgcn_mfma_i32_16x16x64_i8( \
                FA2[mf], FB[nf], acc[4 + mf][nf], 0, 0, 0); \
    __builtin_amdgcn_s_setprio(0); \
  } while (0)

// one pipelined tile: stage (T+3), read frags(T+1) -> NXT, MFMA(T) on CUR
#define TILE_BODY(T, CA, CA2, CB, NA, NA2, NB) do { \
    const int kS = ((T) + 3 < NT ? (T) + 3 : NT - 1) * BK; \
    const int rs = ((T) + 1 < NT ? (T) + 1 : NT - 1) & 3; \
    STAGE_TILE(((T) + 3) & 3, kS); \
    READ_FRAGS(rs, NA, NA2, NB); \
    MFMA_TILE(CA, CA2, CB); \
    asm volatile("s_waitcnt vmcnt(4)" ::: "memory"); \
    __builtin_amdgcn_s_barrier(); \
  } while (0)

    // ---- prologue: stage tiles 0,1,2 -> slots 0,1,2; retire t0,t1; read frags(0) ----
    STAGE_TILE(0, 0);
    STAGE_TILE(1, BK);
    STAGE_TILE(2, 2 * BK);
    asm volatile("s_waitcnt vmcnt(4)" ::: "memory");
    __builtin_amdgcn_s_barrier();

    int4v aA[4], a2A[4], bA[4];   // fragment double-buffer, set A
    int4v aB[4], a2B[4], bB[4];   // set B
    READ_FRAGS(0, aA, a2A, bA);

    for (int t = 0; t < NT; t += 2) {
        TILE_BODY(t,     aA, a2A, bA, aB, a2B, bB);
        TILE_BODY(t + 1, aB, a2B, bB, aA, a2A, bA);
    }

    // ---- epilogue: dequant (per-row scale) + bias + relu, f32 store ----
    float bv[4];
    #pragma unroll
    for (int nf = 0; nf < 4; ++nf)
        bv[nf] = bias[bn + wn * 64 + nf * 16 + (lane & 15)];
    #pragma unroll
    for (int mf = 0; mf < 8; ++mf) {
        const int row0 = bm + wm * 128 + mf * 16 + (lane >> 4) * 4;
        float sr[4];
        #pragma unroll
        for (int r = 0; r < 4; ++r) sr[r] = xsc[row0 + r];
        #pragma unroll
        for (int nf = 0; nf < 4; ++nf) {
            const int col = bn + wn * 64 + nf * 16 + (lane & 15);
            float* cp = C + (size_t)row0 * N_DIM + col;
            #pragma unroll
            for (int r = 0; r < 4; ++r) {
                float v = (float)acc[mf][nf][r] * sr[r] + bv[nf];
                cp[(size_t)r * N_DIM] = v > 0.f ? v : 0.f;
            }
        }
    }
}

// ---------------- fallback (only if ws_size too small): naive tiled fp32 -------------
__global__ void naive_kernel(const float* __restrict__ x, const float* __restrict__ w,
                             const float* __restrict__ b, float* __restrict__ out) {
    __shared__ float xs[16][16];
    __shared__ float ws[16][17];
    const int row = blockIdx.y * 16 + threadIdx.y;
    const int col = blockIdx.x * 16 + threadIdx.x;
    float acc = 0.f;
    for (int k0 = 0; k0 < K_DIM; k0 += 16) {
        xs[threadIdx.y][threadIdx.x] = x[(size_t)row * K_DIM + k0 + threadIdx.x];
        float wv = w[(size_t)(k0 + threadIdx.y) * N_DIM + col];
        ws[threadIdx.y][threadIdx.x] = wv > 0.f ? 1.f : (wv < 0.f ? -1.f : 0.f);
        __syncthreads();
        #pragma unroll
        for (int kk = 0; kk < 16; ++kk) acc += xs[threadIdx.y][kk] * ws[kk][threadIdx.x];
        __syncthreads();
    }
    float v = acc + b[col];
    out[(size_t)row * N_DIM + col] = v > 0.f ? v : 0.f;
}

extern "C" void kernel_launch(void* const* d_in, const int* in_sizes, int n_in,
                              void* d_out, int out_size, void* d_ws, size_t ws_size,
                              hipStream_t stream) {
    const float* x = (const float*)d_in[0];
    const float* w = (const float*)d_in[1];
    const float* b = (const float*)d_in[2];
    float* out = (float*)d_out;

    const size_t xq_bytes = (size_t)M_DIM * K_DIM;                 // 32 MiB i8
    const size_t wT_bytes = (size_t)K_DIM * N_DIM;                 // 16 MiB i8
    const size_t xs_bytes = (size_t)M_DIM * sizeof(float);         // 32 KiB

    if (ws_size >= xq_bytes + wT_bytes + xs_bytes) {
        signed char* xq = (signed char*)d_ws;
        signed char* wT = (signed char*)((char*)d_ws + xq_bytes);
        float*       xs = (float*)((char*)d_ws + xq_bytes + wT_bytes);
        quant_x_kernel<<<M_DIM, 256, 0, stream>>>(x, xq, xs);
        cvt_w_kernel<<<dim3(N_DIM / 64, K_DIM / 64), 256, 0, stream>>>(w, wT);
        gemm_i8_kernel<<<(M_DIM / BM) * (N_DIM / BN), 512, 0, stream>>>(xq, wT, xs, b, out);
    } else {
        naive_kernel<<<dim3(N_DIM / 16, M_DIM / 16), dim3(16, 16), 0, stream>>>(x, w, b, out);
    }
}

// Round 17
// 198.398 us; speedup vs baseline: 1.0890x; 1.0890x over previous
//
#include <hip/hip_runtime.h>
#include <hip/hip_bf16.h>
#include <stdint.h>

#define M_DIM 8192
#define N_DIM 4096
#define K_DIM 4096

typedef __attribute__((ext_vector_type(4))) int   int4v;
typedef __attribute__((ext_vector_type(4))) float floatx4;

// ---------------- pre-pass 1: per-row quantize x f32 -> i8, scale = rowmax/127 -------
__global__ __launch_bounds__(256) void quant_x_kernel(const float* __restrict__ x,
                                                      signed char* __restrict__ xq,
                                                      float* __restrict__ xs) {
    const int row = blockIdx.x;
    const int tid = threadIdx.x;
    const int wave = tid >> 6, lane = tid & 63;
    const float4* xr = (const float4*)(x + (size_t)row * K_DIM);

    float4 v[4];
    float m = 0.f;
    #pragma unroll
    for (int j = 0; j < 4; ++j) {
        v[j] = xr[j * 256 + tid];
        m = fmaxf(m, fmaxf(fmaxf(fabsf(v[j].x), fabsf(v[j].y)),
                           fmaxf(fabsf(v[j].z), fabsf(v[j].w))));
    }
    #pragma unroll
    for (int off = 32; off >= 1; off >>= 1) m = fmaxf(m, __shfl_down(m, off));
    __shared__ float wm_s[4];
    if (lane == 0) wm_s[wave] = m;
    __syncthreads();
    const float M = fmaxf(fmaxf(wm_s[0], wm_s[1]), fmaxf(wm_s[2], wm_s[3]));
    const float inv = M > 0.f ? 127.f / M : 0.f;
    if (tid == 0) xs[row] = M > 0.f ? M / 127.f : 0.f;

    char4* xo = (char4*)(xq + (size_t)row * K_DIM);
    #pragma unroll
    for (int j = 0; j < 4; ++j) {
        char4 q;
        q.x = (signed char)__float2int_rn(v[j].x * inv);
        q.y = (signed char)__float2int_rn(v[j].y * inv);
        q.z = (signed char)__float2int_rn(v[j].z * inv);
        q.w = (signed char)__float2int_rn(v[j].w * inv);
        xo[j * 256 + tid] = q;
    }
}

// ------- pre-pass 2: w f32 [K][N] -> sign(w) i8 in MFMA-FRAGMENT-MAJOR layout --------
// Bf chunk (n64, kt) = 4 KB: [nf 0..3][lane 0..63][16 B], where the 16 bytes are
//   B^T[n64*64 + nf*16 + (lane&15)][kt*64 + (lane>>4)*16 + j], j = 0..15
// -> a wave's B fragment load is 4x contiguous 1KB global_load_dwordx4 (coalesced).
__global__ __launch_bounds__(256) void cvt_w_kernel(const float* __restrict__ w,
                                                    signed char* __restrict__ Bf) {
    __shared__ signed char tile[64][68];   // tile[kk][nn], pad vs column-read conflicts
    const int t  = threadIdx.x;
    const int k0 = blockIdx.y * 64;
    const int n0 = blockIdx.x * 64;
    #pragma unroll
    for (int p = 0; p < 4; ++p) {
        int kk = p * 16 + (t >> 4);
        int nn = (t & 15) * 4;
        float4 v = *reinterpret_cast<const float4*>(&w[(size_t)(k0 + kk) * N_DIM + n0 + nn]);
        tile[kk][nn + 0] = v.x > 0.f ? 1 : (v.x < 0.f ? -1 : 0);
        tile[kk][nn + 1] = v.y > 0.f ? 1 : (v.y < 0.f ? -1 : 0);
        tile[kk][nn + 2] = v.z > 0.f ? 1 : (v.z < 0.f ? -1 : 0);
        tile[kk][nn + 3] = v.w > 0.f ? 1 : (v.w < 0.f ? -1 : 0);
    }
    __syncthreads();
    const int nf   = t >> 6;       // 0..3
    const int lane = t & 63;
    int4v o;
    signed char* op = (signed char*)&o;
    #pragma unroll
    for (int j = 0; j < 16; ++j)
        op[j] = tile[(lane >> 4) * 16 + j][nf * 16 + (lane & 15)];
    const size_t chunk = ((size_t)blockIdx.x * (K_DIM / 64) + blockIdx.y) * 4096;
    *reinterpret_cast<int4v*>(Bf + chunk + nf * 1024 + lane * 16) = o;
}

// =====================================================================================
// 256x256 i8 GEMM, B DIRECT-TO-REGISTER from fragment-major layout (NO B in LDS):
//   C = relu( xs[row] * (Xq * signW^T) + bias )
// 8 waves (2M x 4N), 128x64 per wave. A: LDS, 3 slots, staged TWO tiles ahead (r11's
// proven scheme); swizzle f(row)=((row>>1)&3)<<4 (verified 0-conflict).
// B: per wave 4x contiguous-1KB global loads from Bf (L2-resident), double-buffered in
// registers, loaded ONE tile ahead (~2000 cyc slack >> L2 latency).
// Per tile t: stage A(t+2) (2 GLD) ; load B(t+1)->regs (4 loads) ; 8 A ds_reads ;
//             32 MFMA (B regs ready since last tile) ; vmcnt(6) ; barrier.
// vmcnt ledger (FIFO): end of tile t keeps the 6 newest = [A(t+2)x2, B(t+1)x4];
// vmcnt(6) retires A(t+1) (issued t-1) and B(t) -- each issued a full tile ago.
// LDS traffic/CU/tile: 64 KB read + 16 KB write (was 96+32) -> serial model ~1950 cyc.
// =====================================================================================
#define BM 256
#define BN 256
#define BK 64
#define NT (K_DIM / BK)

#define GLD(gsrc, ldst) __builtin_amdgcn_global_load_lds( \
    (const __attribute__((address_space(1))) unsigned int*)(gsrc), \
    (__attribute__((address_space(3))) unsigned int*)(ldst), 16, 0, 0)

__global__ __launch_bounds__(512, 2) void gemm_i8_kernel(
    const signed char* __restrict__ A,   // [M][K] i8 (quantized x)
    const signed char* __restrict__ Bf,  // fragment-major sign(w)
    const float* __restrict__ xsc,       // [M] row scales
    const float* __restrict__ bias,
    float* __restrict__ C)               // [M][N] f32
{
    __shared__ signed char As[3][256 * 64];   // 48 KiB total

    const int tid  = threadIdx.x;
    const int wave = tid >> 6;
    const int lane = tid & 63;
    const int wm   = wave >> 2;        // 0..1 : wave M-half (rows wm*128..+127)
    const int wn   = wave & 3;         // 0..3 : wave N-slot (cols wn*64..+63)

    // XCD-bijective swizzle (nwg = 512, divisible by 8)
    const int bid  = blockIdx.x;
    const int sbid = (bid & 7) * 64 + (bid >> 3);
    const int tn   = sbid & 15;
    const int tm   = sbid >> 4;
    const int bm   = tm * BM;
    const int bn   = tn * BN;

    // A staging (write side of swizzle): sweep s covers dest rows s*128..+127;
    // row = (tid>>2) + s*128; source col = ((tid&3) ^ ((tid>>3)&3)) * 16
    const int srow = tid >> 2;
    const int scol = ((tid & 3) ^ ((tid >> 3) & 3)) * 16;

    // A fragment read offsets (read side of swizzle)
    const int laneRow = (lane & 15) * 64;
    const int colX = ((lane >> 4) * 16) ^ (((lane >> 1) & 3) << 4);
    const int Abase = wm * 128 * 64;   // wave's A row base (bytes)

    // B fragment-major base for this wave's n64 slice
    const signed char* bfb = Bf + ((size_t)((bn >> 6) + wn) * (K_DIM / 64)) * 4096
                                + lane * 16;

    int4v acc[8][4] = {};

#define STAGE_A(KOFS, SLOT) do { \
    GLD(A + (size_t)(bm + srow) * K_DIM + (KOFS) + scol, As[SLOT] + wave * 1024); \
    GLD(A + (size_t)(bm + 128 + srow) * K_DIM + (KOFS) + scol, \
        As[SLOT] + 8192 + wave * 1024); \
  } while (0)

#define LOAD_B(SLOT, KT) do { \
    const signed char* _b = bfb + (size_t)(KT) * 4096; \
    SLOT[0] = *(const int4v*)(_b + 0 * 1024); \
    SLOT[1] = *(const int4v*)(_b + 1 * 1024); \
    SLOT[2] = *(const int4v*)(_b + 2 * 1024); \
    SLOT[3] = *(const int4v*)(_b + 3 * 1024); \
  } while (0)

#define READ_A() do { \
    a[0]  = *(const int4v*)(Ar + Abase + (0*16)*64 + laneRow + colX); \
    a[1]  = *(const int4v*)(Ar + Abase + (1*16)*64 + laneRow + colX); \
    a[2]  = *(const int4v*)(Ar + Abase + (2*16)*64 + laneRow + colX); \
    a[3]  = *(const int4v*)(Ar + Abase + (3*16)*64 + laneRow + colX); \
    a2[0] = *(const int4v*)(Ar + Abase + ((64+0*16))*64 + laneRow + colX); \
    a2[1] = *(const int4v*)(Ar + Abase + ((64+1*16))*64 + laneRow + colX); \
    a2[2] = *(const int4v*)(Ar + Abase + ((64+2*16))*64 + laneRow + colX); \
    a2[3] = *(const int4v*)(Ar + Abase + ((64+3*16))*64 + laneRow + colX); \
  } while (0)

#define MFMA_T(BREG) do { \
    __builtin_amdgcn_s_setprio(1); \
    _Pragma("unroll") \
    for (int mf = 0; mf < 4; ++mf) \
        _Pragma("unroll") \
        for (int nf = 0; nf < 4; ++nf) \
            acc[mf][nf] = __builtin_amdgcn_mfma_i32_16x16x64_i8( \
                a[mf], BREG[nf], acc[mf][nf], 0, 0, 0); \
    _Pragma("unroll") \
    for (int mf = 0; mf < 4; ++mf) \
        _Pragma("unroll") \
        for (int nf = 0; nf < 4; ++nf) \
            acc[4 + mf][nf] = __builtin_amdgcn_mfma_i32_16x16x64_i8( \
                a2[mf], BREG[nf], acc[4 + mf][nf], 0, 0, 0); \
    __builtin_amdgcn_s_setprio(0); \
  } while (0)

// tile body: stage A(T+2); load B(T+1) into BNXT; read A(T); MFMA with BCUR
#define TILE_BODY(T, BCUR, BNXT) do { \
    const char* Ar = (const char*)As[(T) % 3]; \
    const int kA = ((T) + 2 < NT ? (T) + 2 : NT - 1) * BK; \
    const int kB = ((T) + 1 < NT ? (T) + 1 : NT - 1); \
    STAGE_A(kA, ((T) + 2) % 3); \
    LOAD_B(BNXT, kB); \
    READ_A(); \
    MFMA_T(BCUR); \
    asm volatile("s_waitcnt vmcnt(6)" ::: "memory"); \
    __builtin_amdgcn_s_barrier(); \
  } while (0)

    // ---- prologue: stage A(0),A(1); load B(0); drain; barrier ----
    STAGE_A(0,  0);
    STAGE_A(BK, 1);
    int4v bX[4], bY[4];   // B register double-buffer (static names)
    LOAD_B(bX, 0);
    asm volatile("s_waitcnt vmcnt(0)" ::: "memory");
    __builtin_amdgcn_s_barrier();

    int4v a[4], a2[4];

    for (int t = 0; t < NT; t += 2) {
        TILE_BODY(t,     bX, bY);
        TILE_BODY(t + 1, bY, bX);
    }

    // ---- epilogue: dequant (per-row scale) + bias + relu, f32 store ----
    float bv[4];
    #pragma unroll
    for (int nf = 0; nf < 4; ++nf)
        bv[nf] = bias[bn + wn * 64 + nf * 16 + (lane & 15)];
    #pragma unroll
    for (int mf = 0; mf < 8; ++mf) {
        const int row0 = bm + wm * 128 + mf * 16 + (lane >> 4) * 4;
        float sr[4];
        #pragma unroll
        for (int r = 0; r < 4; ++r) sr[r] = xsc[row0 + r];
        #pragma unroll
        for (int nf = 0; nf < 4; ++nf) {
            const int col = bn + wn * 64 + nf * 16 + (lane & 15);
            float* cp = C + (size_t)row0 * N_DIM + col;
            #pragma unroll
            for (int r = 0; r < 4; ++r) {
                float v = (float)acc[mf][nf][r] * sr[r] + bv[nf];
                cp[(size_t)r * N_DIM] = v > 0.f ? v : 0.f;
            }
        }
    }
}

// ---------------- fallback (only if ws_size too small): naive tiled fp32 -------------
__global__ void naive_kernel(const float* __restrict__ x, const float* __restrict__ w,
                             const float* __restrict__ b, float* __restrict__ out) {
    __shared__ float xs[16][16];
    __shared__ float ws[16][17];
    const int row = blockIdx.y * 16 + threadIdx.y;
    const int col = blockIdx.x * 16 + threadIdx.x;
    float acc = 0.f;
    for (int k0 = 0; k0 < K_DIM; k0 += 16) {
        xs[threadIdx.y][threadIdx.x] = x[(size_t)row * K_DIM + k0 + threadIdx.x];
        float wv = w[(size_t)(k0 + threadIdx.y) * N_DIM + col];
        ws[threadIdx.y][threadIdx.x] = wv > 0.f ? 1.f : (wv < 0.f ? -1.f : 0.f);
        __syncthreads();
        #pragma unroll
        for (int kk = 0; kk < 16; ++kk) acc += xs[threadIdx.y][kk] * ws[kk][threadIdx.x];
        __syncthreads();
    }
    float v = acc + b[col];
    out[(size_t)row * N_DIM + col] = v > 0.f ? v : 0.f;
}

extern "C" void kernel_launch(void* const* d_in, const int* in_sizes, int n_in,
                              void* d_out, int out_size, void* d_ws, size_t ws_size,
                              hipStream_t stream) {
    const float* x = (const float*)d_in[0];
    const float* w = (const float*)d_in[1];
    const float* b = (const float*)d_in[2];
    float* out = (float*)d_out;

    const size_t xq_bytes = (size_t)M_DIM * K_DIM;                 // 32 MiB i8
    const size_t bf_bytes = (size_t)K_DIM * N_DIM;                 // 16 MiB i8
    const size_t xs_bytes = (size_t)M_DIM * sizeof(float);         // 32 KiB

    if (ws_size >= xq_bytes + bf_bytes + xs_bytes) {
        signed char* xq = (signed char*)d_ws;
        signed char* Bf = (signed char*)((char*)d_ws + xq_bytes);
        float*       xs = (float*)((char*)d_ws + xq_bytes + bf_bytes);
        quant_x_kernel<<<M_DIM, 256, 0, stream>>>(x, xq, xs);
        cvt_w_kernel<<<dim3(N_DIM / 64, K_DIM / 64), 256, 0, stream>>>(w, Bf);
        gemm_i8_kernel<<<(M_DIM / BM) * (N_DIM / BN), 512, 0, stream>>>(xq, Bf, xs, b, out);
    } else {
        naive_kernel<<<dim3(N_DIM / 16, M_DIM / 16), dim3(16, 16), 0, stream>>>(x, w, b, out);
    }
}

// Round 18
// 179.249 us; speedup vs baseline: 1.2054x; 1.1068x over previous
//
#include <hip/hip_runtime.h>
#include <hip/hip_bf16.h>
#include <stdint.h>

#define M_DIM 8192
#define N_DIM 4096
#define K_DIM 4096

typedef __attribute__((ext_vector_type(4))) int   int4v;
typedef __attribute__((ext_vector_type(4))) float floatx4;

// ---------------- fused pre-pass: quant_x (blocks 0..8191) + cvt_w (8192..12287) -----
// quant: per-row quantize x f32 -> i8, scale = rowmax/127 (exact sign(w) in GEMM B).
// cvt_w: w f32 [K][N] -> sign(w) i8 transposed [N][K] via LDS transpose.
// Independent outputs -> safe to run concurrently in one grid (saves a launch gap and
// overlaps the two memory streams' tails).
__global__ __launch_bounds__(256) void prep_kernel(const float* __restrict__ x,
                                                   const float* __restrict__ w,
                                                   signed char* __restrict__ xq,
                                                   float* __restrict__ xs,
                                                   signed char* __restrict__ wT) {
    __shared__ signed char tile[64][68];   // cvt_w transpose buffer (pad vs conflicts)
    __shared__ float wm_s[4];
    const int t = threadIdx.x;

    if (blockIdx.x < M_DIM) {
        // ---------------- quant_x ----------------
        const int row = blockIdx.x;
        const int wave = t >> 6, lane = t & 63;
        const float4* xr = (const float4*)(x + (size_t)row * K_DIM);

        float4 v[4];
        float m = 0.f;
        #pragma unroll
        for (int j = 0; j < 4; ++j) {
            v[j] = xr[j * 256 + t];
            m = fmaxf(m, fmaxf(fmaxf(fabsf(v[j].x), fabsf(v[j].y)),
                               fmaxf(fabsf(v[j].z), fabsf(v[j].w))));
        }
        #pragma unroll
        for (int off = 32; off >= 1; off >>= 1) m = fmaxf(m, __shfl_down(m, off));
        if (lane == 0) wm_s[wave] = m;
        __syncthreads();
        const float M = fmaxf(fmaxf(wm_s[0], wm_s[1]), fmaxf(wm_s[2], wm_s[3]));
        const float inv = M > 0.f ? 127.f / M : 0.f;
        if (t == 0) xs[row] = M > 0.f ? M / 127.f : 0.f;

        char4* xo = (char4*)(xq + (size_t)row * K_DIM);
        #pragma unroll
        for (int j = 0; j < 4; ++j) {
            char4 q;
            q.x = (signed char)__float2int_rn(v[j].x * inv);
            q.y = (signed char)__float2int_rn(v[j].y * inv);
            q.z = (signed char)__float2int_rn(v[j].z * inv);
            q.w = (signed char)__float2int_rn(v[j].w * inv);
            xo[j * 256 + t] = q;
        }
    } else {
        // ---------------- cvt_w ----------------
        const int b  = blockIdx.x - M_DIM;       // 0 .. 4095
        const int n0 = (b & 63) * 64;            // N_DIM/64 = 64
        const int k0 = (b >> 6) * 64;
        #pragma unroll
        for (int p = 0; p < 4; ++p) {
            int kk = p * 16 + (t >> 4);
            int nn = (t & 15) * 4;
            float4 v = *reinterpret_cast<const float4*>(
                &w[(size_t)(k0 + kk) * N_DIM + n0 + nn]);
            tile[kk][nn + 0] = v.x > 0.f ? 1 : (v.x < 0.f ? -1 : 0);
            tile[kk][nn + 1] = v.y > 0.f ? 1 : (v.y < 0.f ? -1 : 0);
            tile[kk][nn + 2] = v.z > 0.f ? 1 : (v.z < 0.f ? -1 : 0);
            tile[kk][nn + 3] = v.w > 0.f ? 1 : (v.w < 0.f ? -1 : 0);
        }
        __syncthreads();
        const int r = t >> 2;          // local n row
        const int c = (t & 3) * 16;    // local k byte
        int4v o;
        signed char* op = (signed char*)&o;
        #pragma unroll
        for (int j = 0; j < 16; ++j) op[j] = tile[c + j][r];
        *reinterpret_cast<int4v*>(&wT[(size_t)(n0 + r) * K_DIM + k0 + c]) = o;
    }
}

// =====================================================================================
// 256x256 i8 GEMM, 1024 threads / 16 waves (4M x 4N, 64x64 per wave) -- BEST (r14):
//   C = relu( xs[row] * (Xq * signW^T) + bias )
// 3 LDS slots per operand, staged TWO tiles ahead, one barrier per tile.
// LDS: As[3][256*64] + Bs[3][256*64] = 96 KiB. Swizzle f(row)=((row>>1)&3)<<4
// (16-row fragments at the half-wave bank floor -- verified 0-conflict).
// Per tile t: 8 ds_reads ; stage {A,B}(t+2) (2 GLD) ; 16 MFMA ; vmcnt(2) ; barrier.
// vmcnt ledger: outstanding at tile end = {A,B}(t+1) (issued t-1) + {A,B}(t+2)
// (issued t) = 4; vmcnt(2) retires the t+1 pair (issued a full tile ago: no stall).
// Measured plateau: ~2540 cyc/tile == serial MFMA(1306)+LDS-read(1024)+write(256);
// 10 structural variants (r5-r17) bracket 135-152 us -> practical floor of this
// structure. MfmaUtil ~46%, conflicts 0.
// =====================================================================================
#define BM 256
#define BN 256
#define BK 64
#define NT (K_DIM / BK)

#define GLD(gsrc, ldst) __builtin_amdgcn_global_load_lds( \
    (const __attribute__((address_space(1))) unsigned int*)(gsrc), \
    (__attribute__((address_space(3))) unsigned int*)(ldst), 16, 0, 0)

__global__ __launch_bounds__(1024, 4) void gemm_i8_kernel(
    const signed char* __restrict__ A,   // [M][K] i8 (quantized x)
    const signed char* __restrict__ BT,  // [N][K] i8 = sign(w)^T
    const float* __restrict__ xsc,       // [M] row scales
    const float* __restrict__ bias,
    float* __restrict__ C)               // [M][N] f32
{
    __shared__ signed char As[3][256 * 64];   // 48 KiB
    __shared__ signed char Bs[3][256 * 64];   // 48 KiB

    const int tid  = threadIdx.x;
    const int wave = tid >> 6;
    const int lane = tid & 63;
    const int wm   = wave >> 2;        // 0..3 : wave M-slot (rows wm*64..+63)
    const int wn   = wave & 3;         // 0..3 : wave N-slot (cols wn*64..+63)

    // XCD-bijective swizzle (nwg = 512, divisible by 8)
    const int bid  = blockIdx.x;
    const int sbid = (bid & 7) * 64 + (bid >> 3);
    const int tn   = sbid & 15;
    const int tm   = sbid >> 4;
    const int bm   = tm * BM;
    const int bn   = tn * BN;

    // staging (write side of swizzle): dest linear o = tid*16 over [256][64];
    // row = tid>>2; source col = ((tid&3) ^ ((tid>>3)&3)) * 16  [row bits 2:1 = tid 4:3]
    const int srow = tid >> 2;
    const int scol = ((tid & 3) ^ ((tid >> 3) & 3)) * 16;

    // fragment read offsets (read side of swizzle)
    const int laneRow = (lane & 15) * 64;
    const int colX = ((lane >> 4) * 16) ^ (((lane >> 1) & 3) << 4);
    const int Abase = wm * 64 * 64;    // wave's A row base (bytes)
    const int Bbase = wn * 64 * 64;    // wave's B row base (bytes)

    int4v acc[4][4] = {};              // 64 VGPRs: 4x4 of 16x16 frags = 64x64

#define STAGE_T(G, R0, KOFS, LDSLOT) do { \
    GLD((G) + (size_t)((R0) + srow) * K_DIM + (KOFS) + scol, (LDSLOT) + wave * 1024); \
  } while (0)

    // ---- prologue: stage tiles 0,1 -> slots 0,1; retire tile-0 pair, keep tile-1 ----
    STAGE_T(A,  bm, 0,  As[0]);
    STAGE_T(BT, bn, 0,  Bs[0]);
    STAGE_T(A,  bm, BK, As[1]);
    STAGE_T(BT, bn, BK, Bs[1]);
    asm volatile("s_waitcnt vmcnt(2)" ::: "memory");
    __builtin_amdgcn_s_barrier();

    int4v a[4];    // A frags (reused per tile)
    int4v b[4];    // B frags

    int rd = 0;    // t % 3
    int st = 2;    // (t+2) % 3

    for (int t = 0; t < NT; ++t) {
        const char* Ar = (const char*)As[rd];
        const char* Br = (const char*)Bs[rd];
        const int kS = (t + 2 < NT ? t + 2 : NT - 1) * BK;   // tail reloads never read

        // ---- 8 ds_reads, consumption order ----
        a[0] = *(const int4v*)(Ar + Abase + (0*16)*64 + laneRow + colX);
        b[0] = *(const int4v*)(Br + Bbase + (0*16)*64 + laneRow + colX);
        b[1] = *(const int4v*)(Br + Bbase + (1*16)*64 + laneRow + colX);
        b[2] = *(const int4v*)(Br + Bbase + (2*16)*64 + laneRow + colX);
        b[3] = *(const int4v*)(Br + Bbase + (3*16)*64 + laneRow + colX);
        a[1] = *(const int4v*)(Ar + Abase + (1*16)*64 + laneRow + colX);
        a[2] = *(const int4v*)(Ar + Abase + (2*16)*64 + laneRow + colX);
        a[3] = *(const int4v*)(Ar + Abase + (3*16)*64 + laneRow + colX);

        // ---- stage {A,B}(t+2) into slot (t+2)%3 (readers ran in tile t-1) ----
        STAGE_T(A,  bm, kS, As[st]);
        STAGE_T(BT, bn, kS, Bs[st]);

        // ---- 16 MFMA (compiler-counted lgkm waits interleave with reads) ----
        __builtin_amdgcn_s_setprio(1);
        #pragma unroll
        for (int mf = 0; mf < 4; ++mf)
            #pragma unroll
            for (int nf = 0; nf < 4; ++nf)
                acc[mf][nf] = __builtin_amdgcn_mfma_i32_16x16x64_i8(
                    a[mf], b[nf], acc[mf][nf], 0, 0, 0);
        __builtin_amdgcn_s_setprio(0);

        // retire {A,B}(t+1) (issued a full tile ago); keep {A,B}(t+2) in flight
        asm volatile("s_waitcnt vmcnt(2)" ::: "memory");
        __builtin_amdgcn_s_barrier();

        rd = (rd == 2) ? 0 : rd + 1;
        st = (st == 2) ? 0 : st + 1;
    }

    // ---- epilogue: dequant (per-row scale) + bias + relu, f32 store ----
    float bv[4];
    #pragma unroll
    for (int nf = 0; nf < 4; ++nf)
        bv[nf] = bias[bn + wn * 64 + nf * 16 + (lane & 15)];
    #pragma unroll
    for (int mf = 0; mf < 4; ++mf) {
        const int row0 = bm + wm * 64 + mf * 16 + (lane >> 4) * 4;
        float sr[4];
        #pragma unroll
        for (int r = 0; r < 4; ++r) sr[r] = xsc[row0 + r];
        #pragma unroll
        for (int nf = 0; nf < 4; ++nf) {
            const int col = bn + wn * 64 + nf * 16 + (lane & 15);
            float* cp = C + (size_t)row0 * N_DIM + col;
            #pragma unroll
            for (int r = 0; r < 4; ++r) {
                float v = (float)acc[mf][nf][r] * sr[r] + bv[nf];
                cp[(size_t)r * N_DIM] = v > 0.f ? v : 0.f;
            }
        }
    }
}

// ---------------- fallback (only if ws_size too small): naive tiled fp32 -------------
__global__ void naive_kernel(const float* __restrict__ x, const float* __restrict__ w,
                             const float* __restrict__ b, float* __restrict__ out) {
    __shared__ float xs[16][16];
    __shared__ float ws[16][17];
    const int row = blockIdx.y * 16 + threadIdx.y;
    const int col = blockIdx.x * 16 + threadIdx.x;
    float acc = 0.f;
    for (int k0 = 0; k0 < K_DIM; k0 += 16) {
        xs[threadIdx.y][threadIdx.x] = x[(size_t)row * K_DIM + k0 + threadIdx.x];
        float wv = w[(size_t)(k0 + threadIdx.y) * N_DIM + col];
        ws[threadIdx.y][threadIdx.x] = wv > 0.f ? 1.f : (wv < 0.f ? -1.f : 0.f);
        __syncthreads();
        #pragma unroll
        for (int kk = 0; kk < 16; ++kk) acc += xs[threadIdx.y][kk] * ws[kk][threadIdx.x];
        __syncthreads();
    }
    float v = acc + b[col];
    out[(size_t)row * N_DIM + col] = v > 0.f ? v : 0.f;
}

extern "C" void kernel_launch(void* const* d_in, const int* in_sizes, int n_in,
                              void* d_out, int out_size, void* d_ws, size_t ws_size,
                              hipStream_t stream) {
    const float* x = (const float*)d_in[0];
    const float* w = (const float*)d_in[1];
    const float* b = (const float*)d_in[2];
    float* out = (float*)d_out;

    const size_t xq_bytes = (size_t)M_DIM * K_DIM;                 // 32 MiB i8
    const size_t wT_bytes = (size_t)K_DIM * N_DIM;                 // 16 MiB i8
    const size_t xs_bytes = (size_t)M_DIM * sizeof(float);         // 32 KiB

    if (ws_size >= xq_bytes + wT_bytes + xs_bytes) {
        signed char* xq = (signed char*)d_ws;
        signed char* wT = (signed char*)((char*)d_ws + xq_bytes);
        float*       xs = (float*)((char*)d_ws + xq_bytes + wT_bytes);
        prep_kernel<<<M_DIM + (N_DIM / 64) * (K_DIM / 64), 256, 0, stream>>>(
            x, w, xq, xs, wT);
        gemm_i8_kernel<<<(M_DIM / BM) * (N_DIM / BN), 1024, 0, stream>>>(
            xq, wT, xs, b, out);
    } else {
        naive_kernel<<<dim3(N_DIM / 16, M_DIM / 16), dim3(16, 16), 0, stream>>>(x, w, b, out);
    }
}